// Round 16
// baseline (56.668 us; speedup 1.0000x reference)
//
#include <hip/hip_runtime.h>
#include <hip/hip_bf16.h>
#include <cstddef>
#include <cstdint>

// T=128, B=8, E=1024, H=16, D=64. GEMMs 1024^3.
// Pipeline (4 dispatches):
//   tof16ow (ow only) -> proj4rs (reads f32 inputs directly; f32->f16 fused
//   into async reg-staging; 64x128 tiles, 3-buf LDS, lgkm-only barriers;
//   epilogue emits Qh/Kh head-major, VhT transposed, CB/DD) -> attn -> out.
// r15->r16: proj4's invariant ~38us traced to reading tof16's fresh f16
// workspace via global_load_lds (out_kernel, same template+shape on old
// inputs, runs 2-6x faster). proj4 now reads ORIGINAL f32 inputs (clean
// lines) with reg-staged loads issued a phase ahead; barriers drain lgkm
// only so reg-loads stay in flight (the r4 failure mode removed).

typedef _Float16 f16;
typedef __attribute__((ext_vector_type(8))) _Float16 f16x8;
typedef __attribute__((ext_vector_type(4))) float f32x4;

#define GLOBAL_TO_LDS(g, l) __builtin_amdgcn_global_load_lds( \
    (const __attribute__((address_space(1))) void*)(g),       \
    (__attribute__((address_space(3))) void*)(l), 16, 0, 0)

#define PIPE_SYNC(N) do {                                      \
    asm volatile("s_waitcnt vmcnt(" #N ")" ::: "memory");      \
    __builtin_amdgcn_s_barrier();                              \
    __builtin_amdgcn_sched_barrier(0);                         \
} while (0)

// lgkm-only barrier: ds_writes visible across waves, reg-loads stay in flight
#define LBAR() do {                                            \
    asm volatile("s_waitcnt lgkmcnt(0)" ::: "memory");         \
    __builtin_amdgcn_s_barrier();                              \
    __builtin_amdgcn_sched_barrier(0);                         \
} while (0)

// ---------------------------------------------------------------------------
// fp32 -> fp16 for ow only (1M elems). grid 512.
// ---------------------------------------------------------------------------
__global__ __launch_bounds__(256) void tof16ow_kernel(const float* __restrict__ s,
                                                      f16* __restrict__ d)
{
    const int i = (blockIdx.x * 256 + threadIdx.x) * 8;
    const float4 a = *(const float4*)(s + i);
    const float4 b = *(const float4*)(s + i + 4);
    f16x8 o;
    o[0] = (f16)a.x; o[1] = (f16)a.y; o[2] = (f16)a.z; o[3] = (f16)a.w;
    o[4] = (f16)b.x; o[5] = (f16)b.y; o[6] = (f16)b.z; o[7] = (f16)b.w;
    *(f16x8*)(d + i) = o;
}

// ---------------------------------------------------------------------------
// 3-deep counted-vmcnt MFMA GEMM core (f16 operands, gload_lds staging).
// Used by out_kernel (proven fast on non-fresh inputs). NT K-steps of 64.
// ---------------------------------------------------------------------------
template <int TM, int TN, int NT>
__device__ __forceinline__ void gemm3ph_acc(const f16* __restrict__ A,
                                            const f16* __restrict__ B,
                                            int kbeg, int m0, int n0,
                                            f32x4 (&acc)[TM / 32][TN / 32])
{
    constexpr int AITS = TM / 32, BITS = TN / 32;
    constexpr int LD = AITS + BITS;
    constexpr int FM = TM / 32, FN = TN / 32;
    constexpr int T3 = (NT - 1) / 3;
    constexpr int REM = NT - 3 * T3;
    __shared__ __attribute__((aligned(16))) f16 As0[TM * 64];
    __shared__ __attribute__((aligned(16))) f16 As1[TM * 64];
    __shared__ __attribute__((aligned(16))) f16 As2[TM * 64];
    __shared__ __attribute__((aligned(16))) f16 Bs0[TN * 64];
    __shared__ __attribute__((aligned(16))) f16 Bs1[TN * 64];
    __shared__ __attribute__((aligned(16))) f16 Bs2[TN * 64];
    const int tid = threadIdx.x;
    const int wave = tid >> 6, lane = tid & 63;
    const int wr = wave >> 1, wc = wave & 1;
    const int l16 = lane & 15, lk = lane >> 4;

    auto stage = [&](f16* as_, f16* bs_, int k0) {
#pragma unroll
        for (int it = 0; it < AITS; ++it) {
            const int ebase = it * 2048 + wave * 512;
            const int e = ebase + lane * 8;
            const int row = e >> 6, slot = (e >> 3) & 7;
            const int scol = (slot ^ (row & 7)) << 3;
            GLOBAL_TO_LDS(A + (size_t)(m0 + row) * 1024 + k0 + scol, as_ + ebase);
        }
#pragma unroll
        for (int it = 0; it < BITS; ++it) {
            const int ebase = it * 2048 + wave * 512;
            const int e = ebase + lane * 8;
            const int row = e >> 6, slot = (e >> 3) & 7;
            const int scol = (slot ^ (row & 7)) << 3;
            GLOBAL_TO_LDS(B + (size_t)(n0 + row) * 1024 + k0 + scol, bs_ + ebase);
        }
    };
    auto compute = [&](const f16* as_, const f16* bs_) {
#pragma unroll
        for (int ksl = 0; ksl < 2; ++ksl) {
            const int s = ksl * 4 + lk;
            f16x8 af[FM], bg[FN];
#pragma unroll
            for (int mi = 0; mi < FM; ++mi) {
                const int r = wr * (TM / 2) + mi * 16 + l16;
                af[mi] = *(const f16x8*)(as_ + r * 64 + ((s ^ (r & 7)) << 3));
            }
#pragma unroll
            for (int ni = 0; ni < FN; ++ni) {
                const int r = wc * (TN / 2) + ni * 16 + l16;
                bg[ni] = *(const f16x8*)(bs_ + r * 64 + ((s ^ (r & 7)) << 3));
            }
            __builtin_amdgcn_s_setprio(1);
#pragma unroll
            for (int mi = 0; mi < FM; ++mi)
#pragma unroll
                for (int ni = 0; ni < FN; ++ni)
                    acc[mi][ni] = __builtin_amdgcn_mfma_f32_16x16x32_f16(
                        af[mi], bg[ni], acc[mi][ni], 0, 0, 0);
            __builtin_amdgcn_s_setprio(0);
        }
    };
    auto sync_steady = [&]() {
        if constexpr (LD == 6) PIPE_SYNC(6);
        else if constexpr (LD == 5) PIPE_SYNC(5);
        else PIPE_SYNC(4);
    };

    stage(As0, Bs0, kbeg);
    stage(As1, Bs1, kbeg + 64);
    int k = kbeg;
#pragma unroll 1
    for (int t = 0; t < 3 * T3; t += 3) {
        sync_steady();
        if (t + 2 < NT) stage(As2, Bs2, k + 128);
        compute(As0, Bs0);
        sync_steady();
        if (t + 3 < NT) stage(As0, Bs0, k + 192);
        compute(As1, Bs1);
        sync_steady();
        if (t + 4 < NT) stage(As1, Bs1, k + 256);
        compute(As2, Bs2);
        k += 192;
    }
    if constexpr (REM == 2) {
        sync_steady();
        compute(As0, Bs0);
        PIPE_SYNC(0);
        compute(As1, Bs1);
    } else {
        PIPE_SYNC(0);
        compute(As0, Bs0);
    }
}

// ---------------------------------------------------------------------------
// proj4rs: 4 projections from f32 inputs, 64x128 tiles, grid 512 (2 blk/CU).
// Staging = async reg-load (f32) -> cvt -> swizzled ds_write (f16).
// Phase t: write(t+1) [compiler vmcnt-waits regs] ; load(t+2) ; compute(t) ;
// LBAR (lgkm only). 3 LDS buffers, one 48-VGPR reg set.
// Epilogues identical to r12 (verified): z=0 Qh+DD, z=1 Kh, z=2 VhT, z=3 CB.
// ---------------------------------------------------------------------------
__global__ __launch_bounds__(256, 2) void proj4rs_kernel(
    const float* __restrict__ query, const float* __restrict__ rel_pe,
    const float* __restrict__ qw, const float* __restrict__ kw,
    const float* __restrict__ vw, const float* __restrict__ rw,
    const float* __restrict__ spk_emb,
    f16* __restrict__ Qh, f16* __restrict__ Kh, f16* __restrict__ VhT,
    float* __restrict__ CB, float* __restrict__ DD)
{
    __shared__ __attribute__((aligned(16))) f16 As0[64 * 64];
    __shared__ __attribute__((aligned(16))) f16 As1[64 * 64];
    __shared__ __attribute__((aligned(16))) f16 As2[64 * 64];
    __shared__ __attribute__((aligned(16))) f16 Bs0[128 * 64];
    __shared__ __attribute__((aligned(16))) f16 Bs1[128 * 64];
    __shared__ __attribute__((aligned(16))) f16 Bs2[128 * 64];

    const int bid = blockIdx.x;
    const int z = (bid & 7) >> 1;
    const int w = ((bid >> 3) << 1) | (bid & 1);   // 0..127
    const int m0 = (w >> 3) << 6;
    const int n0 = (w & 7) << 7;
    const float* A = (z == 3) ? rel_pe : query;
    const float* W = (z == 0) ? qw : (z == 1) ? kw : (z == 2) ? vw : rw;

    const int tid = threadIdx.x;
    const int wave = tid >> 6, lane = tid & 63;
    const int wr = wave >> 1, wc = wave & 1;
    const int l16 = lane & 15, lk = lane >> 4;

    float4 ra[2][2], rb[4][2];
    f32x4 acc[2][4] = {};

    auto load_stage = [&](int k0) {
#pragma unroll
        for (int it = 0; it < 2; ++it) {
            const int e = it * 2048 + wave * 512 + lane * 8;
            const int row = e >> 6, slot = (e >> 3) & 7;
            const float* s = A + (size_t)(m0 + row) * 1024 + k0 + slot * 8;
            ra[it][0] = *(const float4*)s;
            ra[it][1] = *(const float4*)(s + 4);
        }
#pragma unroll
        for (int it = 0; it < 4; ++it) {
            const int e = it * 2048 + wave * 512 + lane * 8;
            const int row = e >> 6, slot = (e >> 3) & 7;
            const float* s = W + (size_t)(n0 + row) * 1024 + k0 + slot * 8;
            rb[it][0] = *(const float4*)s;
            rb[it][1] = *(const float4*)(s + 4);
        }
    };
    auto write_stage = [&](f16* as_, f16* bs_) {
#pragma unroll
        for (int it = 0; it < 2; ++it) {
            const int e = it * 2048 + wave * 512 + lane * 8;
            const int row = e >> 6, slot = (e >> 3) & 7;
            f16x8 o;
            o[0] = (f16)ra[it][0].x; o[1] = (f16)ra[it][0].y;
            o[2] = (f16)ra[it][0].z; o[3] = (f16)ra[it][0].w;
            o[4] = (f16)ra[it][1].x; o[5] = (f16)ra[it][1].y;
            o[6] = (f16)ra[it][1].z; o[7] = (f16)ra[it][1].w;
            *(f16x8*)(as_ + row * 64 + ((slot ^ (row & 7)) << 3)) = o;
        }
#pragma unroll
        for (int it = 0; it < 4; ++it) {
            const int e = it * 2048 + wave * 512 + lane * 8;
            const int row = e >> 6, slot = (e >> 3) & 7;
            f16x8 o;
            o[0] = (f16)rb[it][0].x; o[1] = (f16)rb[it][0].y;
            o[2] = (f16)rb[it][0].z; o[3] = (f16)rb[it][0].w;
            o[4] = (f16)rb[it][1].x; o[5] = (f16)rb[it][1].y;
            o[6] = (f16)rb[it][1].z; o[7] = (f16)rb[it][1].w;
            *(f16x8*)(bs_ + row * 64 + ((slot ^ (row & 7)) << 3)) = o;
        }
    };
    auto compute = [&](const f16* as_, const f16* bs_) {
#pragma unroll
        for (int ksl = 0; ksl < 2; ++ksl) {
            const int s = ksl * 4 + lk;
            f16x8 af[2], bg[4];
#pragma unroll
            for (int mi = 0; mi < 2; ++mi) {
                const int r = wr * 32 + mi * 16 + l16;
                af[mi] = *(const f16x8*)(as_ + r * 64 + ((s ^ (r & 7)) << 3));
            }
#pragma unroll
            for (int ni = 0; ni < 4; ++ni) {
                const int r = wc * 64 + ni * 16 + l16;
                bg[ni] = *(const f16x8*)(bs_ + r * 64 + ((s ^ (r & 7)) << 3));
            }
            __builtin_amdgcn_s_setprio(1);
#pragma unroll
            for (int mi = 0; mi < 2; ++mi)
#pragma unroll
                for (int ni = 0; ni < 4; ++ni)
                    acc[mi][ni] = __builtin_amdgcn_mfma_f32_16x16x32_f16(
                        af[mi], bg[ni], acc[mi][ni], 0, 0, 0);
            __builtin_amdgcn_s_setprio(0);
        }
    };

    f16* Asb[3] = {As0, As1, As2};
    f16* Bsb[3] = {Bs0, Bs1, Bs2};

    // prologue: tile0 -> buf0 (serial), tile1 loads in flight
    load_stage(0);
    write_stage(As0, Bs0);
    load_stage(64);
    LBAR();

#pragma unroll
    for (int t = 0; t < 16; ++t) {
        if (t + 1 < 16) write_stage(Asb[(t + 1) % 3], Bsb[(t + 1) % 3]);
        if (t + 2 < 16) load_stage((t + 2) * 64);
        compute(Asb[t % 3], Bsb[t % 3]);
        LBAR();
    }

    // ---- epilogue (r12-verified) ----
    const int h = (n0 >> 6) + wc;
    if (z == 0) {
        float s0v[4], s1v[4];
#pragma unroll
        for (int ni = 0; ni < 4; ++ni) {
            const int c = (h << 6) + ni * 16 + l16;
            s0v[ni] = spk_emb[c];
            s1v[ni] = spk_emb[1024 + c];
        }
#pragma unroll
        for (int mi = 0; mi < 2; ++mi)
#pragma unroll
            for (int r = 0; r < 4; ++r) {
                const int row = m0 + wr * 32 + mi * 16 + lk * 4 + r;
                const int b = row & 7, t = row >> 3;
                float p0 = 0.f, p1 = 0.f;
#pragma unroll
                for (int ni = 0; ni < 4; ++ni) {
                    const float x = acc[mi][ni][r] + s0v[ni];
                    const int d = ni * 16 + l16;
                    Qh[(size_t)(((b << 4) + h) * 128 + t) * 64 + d] = (f16)x;
                    p0 = fmaf(x, s0v[ni], p0);
                    p1 = fmaf(x, s1v[ni], p1);
                }
#pragma unroll
                for (int off = 1; off < 16; off <<= 1) {
                    p0 += __shfl_xor(p0, off, 64);
                    p1 += __shfl_xor(p1, off, 64);
                }
                if (l16 == 0) {
                    const int n = (b << 4) + h;
                    DD[n * 128 + t] = p0;
                    DD[16384 + n * 128 + t] = p1;
                }
            }
    } else if (z == 3) {
        float s0v[4];
#pragma unroll
        for (int ni = 0; ni < 4; ++ni)
            s0v[ni] = spk_emb[(h << 6) + ni * 16 + l16];
#pragma unroll
        for (int mi = 0; mi < 2; ++mi)
#pragma unroll
            for (int r = 0; r < 4; ++r) {
                const int row = m0 + wr * 32 + mi * 16 + lk * 4 + r;
                const int b = row & 7, j = row >> 3;
                float p = 0.f;
#pragma unroll
                for (int ni = 0; ni < 4; ++ni)
                    p = fmaf(acc[mi][ni][r], s0v[ni], p);
#pragma unroll
                for (int off = 1; off < 16; off <<= 1)
                    p += __shfl_xor(p, off, 64);
                if (l16 == 0)
                    CB[((b << 4) + h) * 128 + j] = p;
            }
    } else {
        f16* dst = (z == 1) ? Kh : VhT;
#pragma unroll
        for (int mi = 0; mi < 2; ++mi)
#pragma unroll
            for (int r = 0; r < 4; ++r) {
                const int row = m0 + wr * 32 + mi * 16 + lk * 4 + r;
                const int b = row & 7, t = row >> 3;
#pragma unroll
                for (int ni = 0; ni < 4; ++ni) {
                    const int d = ni * 16 + l16;
                    const f16 x = (f16)acc[mi][ni][r];
                    if (z == 1)
                        dst[(size_t)(((b << 4) + h) * 128 + t) * 64 + d] = x;
                    else
                        dst[(size_t)(((b << 4) + h) * 64 + d) * 128 + t] = x;
                }
            }
    }
}

// Out projection: 64x64 tiles (2x2 waves), full K, grid 256, writes f32 d_out.
__global__ __launch_bounds__(256) void out_kernel(
    const f16* __restrict__ ATT, const f16* __restrict__ owf,
    float* __restrict__ out)
{
    const int bid = blockIdx.x;
    const int m0 = (bid >> 4) << 6;
    const int n0 = (bid & 15) << 6;
    f32x4 acc[2][2] = {};
    gemm3ph_acc<64, 64, 16>(ATT, owf, 0, m0, n0, acc);
    const int tid = threadIdx.x;
    const int wave = tid >> 6, lane = tid & 63;
    const int wr = wave >> 1, wc = wave & 1;
    const int l16 = lane & 15, lk = lane >> 4;
#pragma unroll
    for (int mi = 0; mi < 2; ++mi)
#pragma unroll
        for (int ni = 0; ni < 2; ++ni)
#pragma unroll
            for (int r = 0; r < 4; ++r) {
                const int row = m0 + wr * 32 + mi * 16 + lk * 4 + r;
                const int col = n0 + wc * 32 + ni * 16 + l16;
                out[(size_t)row * 1024 + col] = acc[mi][ni][r];
            }
}

// ---------------------------------------------------------------------------
// MFMA attention, single-barrier body (verified r11/r12). Block = (n, half).
// a2 = utt * (spk ? dot1 : dot0); a3 = CB[127-i+j] (j<=i); masked score=1e-30.
// ---------------------------------------------------------------------------
__global__ __launch_bounds__(256) void attn_mfma_kernel(
    const f16* __restrict__ Qh, const f16* __restrict__ Kh,
    const f16* __restrict__ VhT,
    const float* __restrict__ CB, const float* __restrict__ DD,
    const int* __restrict__ spk_mask, const float* __restrict__ utt_mask,
    f16* __restrict__ ATT)
{
    __shared__ __attribute__((aligned(16))) char smem[58368];
    f16* nq = (f16*)smem;
    f16* kt = (f16*)(smem + 8192);
    f16* vt = (f16*)(smem + 24576);
    f16* psb = (f16*)(smem + 40960);
    float* cbuf = (float*)(smem + 57344);
    float* ddl  = (float*)(smem + 57856);

    const int bx = blockIdx.x, n = bx >> 1, half = bx & 1;
    const int b = n >> 4, h = n & 15, i0 = half << 6;
    const int tid = threadIdx.x, wave = tid >> 6, lane = tid & 63;
    const int l16 = lane & 15, lk = lane >> 4;
    const int il0 = wave * 16 + lk * 4;
    const size_t hb = (size_t)n * (128 * 64);

#pragma unroll
    for (int it = 0; it < 2; ++it) {
        const int ebase = it * 2048 + wave * 512;
        const int e = ebase + lane * 8;
        const int row = e >> 6, slot = (e >> 3) & 7;
        const int scol = (slot ^ (row & 7)) << 3;
        GLOBAL_TO_LDS(Qh + hb + (size_t)(i0 + row) * 64 + scol, nq + ebase);
    }
#pragma unroll
    for (int it = 0; it < 4; ++it) {
        const int ebase = it * 2048 + wave * 512;
        const int e = ebase + lane * 8;
        const int row = e >> 6, slot = (e >> 3) & 7;
        const int scol = (slot ^ (row & 7)) << 3;
        GLOBAL_TO_LDS(Kh + hb + (size_t)row * 64 + scol, kt + ebase);
    }
#pragma unroll
    for (int it = 0; it < 4; ++it) {
        const int ebase = it * 2048 + wave * 512;
        const int e = ebase + lane * 8;
        const int row = e >> 7, slot = (e >> 3) & 15;
        const int scol = (slot ^ (row & 7)) << 3;
        GLOBAL_TO_LDS(VhT + hb + (size_t)row * 128 + scol, vt + ebase);
    }

    if (tid < 128) {
        cbuf[tid] = CB[n * 128 + tid];
    } else {
        const int t2 = tid - 128;
        ddl[t2] = DD[(t2 >> 6) * 16384 + n * 128 + i0 + (t2 & 63)];
    }

    float du[8][4];
    int   sm[8][4];
#pragma unroll
    for (int ni = 0; ni < 8; ++ni) {
        const int j = ni * 16 + l16;
#pragma unroll
        for (int r = 0; r < 4; ++r) {
            const int i = i0 + il0 + r;
            du[ni][r] = utt_mask[((size_t)n * 128 + i) * 128 + j];
            sm[ni][r] = spk_mask[((size_t)b * 128 + i) * 128 + j];
        }
    }
    __syncthreads();

    const int iw = wave * 16 + l16;
    f16x8 af[2];
#pragma unroll
    for (int ksl = 0; ksl < 2; ++ksl) {
        const int s = ksl * 4 + lk;
        af[ksl] = *(const f16x8*)(nq + iw * 64 + ((s ^ (iw & 7)) << 3));
    }
    f32x4 sacc[8] = {};
#pragma unroll
    for (int ksl = 0; ksl < 2; ++ksl) {
        const int s = ksl * 4 + lk;
#pragma unroll
        for (int ni = 0; ni < 8; ++ni) {
            const int j = ni * 16 + l16;
            const f16x8 bg = *(const f16x8*)(kt + j * 64 + ((s ^ (j & 7)) << 3));
            sacc[ni] = __builtin_amdgcn_mfma_f32_16x16x32_f16(af[ksl], bg, sacc[ni], 0, 0, 0);
        }
    }

    float sc[8][4];
#pragma unroll
    for (int ni = 0; ni < 8; ++ni) {
        const int j = ni * 16 + l16;
#pragma unroll
        for (int r = 0; r < 4; ++r) {
            const int il = il0 + r, i = i0 + il;
            const float a2 = du[ni][r] * (sm[ni][r] ? ddl[64 + il] : ddl[il]);
            const float a3 = (j <= i) ? cbuf[127 - i + j] : 0.f;
            const float v = (sacc[ni][r] + a2 + a3) * 0.125f;
            sc[ni][r] = (j > i) ? 1e-30f : v;
        }
    }
    float inv[4];
    f16* ps = psb + wave * 2048;
#pragma unroll
    for (int r = 0; r < 4; ++r) {
        float m = sc[0][r];
#pragma unroll
        for (int ni = 1; ni < 8; ++ni) m = fmaxf(m, sc[ni][r]);
#pragma unroll
        for (int off = 8; off > 0; off >>= 1) m = fmaxf(m, __shfl_xor(m, off, 64));
        float ssum = 0.f;
#pragma unroll
        for (int ni = 0; ni < 8; ++ni) {
            const float e = __expf(sc[ni][r] - m);
            sc[ni][r] = e;
            ssum += e;
        }
#pragma unroll
        for (int off = 8; off > 0; off >>= 1) ssum += __shfl_xor(ssum, off, 64);
        inv[r] = 1.f / ssum;
    }
#pragma unroll
    for (int ni = 0; ni < 8; ++ni) {
        const int j = ni * 16 + l16;
#pragma unroll
        for (int r = 0; r < 4; ++r) {
            const int il = lk * 4 + r;
            ps[il * 128 + ((((j >> 3) ^ (il & 7)) << 3) | (j & 7))] = (f16)sc[ni][r];
        }
    }

    f16x8 pa[4];
#pragma unroll
    for (int ks = 0; ks < 4; ++ks) {
        const int slot = ks * 4 + lk;
        pa[ks] = *(const f16x8*)(ps + l16 * 128 + ((slot ^ (l16 & 7)) << 3));
    }
    f32x4 oacc[4] = {};
#pragma unroll
    for (int ks = 0; ks < 4; ++ks) {
        const int slot = ks * 4 + lk;
#pragma unroll
        for (int nd = 0; nd < 4; ++nd) {
            const int d = nd * 16 + l16;
            const f16x8 vb = *(const f16x8*)(vt + d * 128 + ((slot ^ (d & 7)) << 3));
            oacc[nd] = __builtin_amdgcn_mfma_f32_16x16x32_f16(pa[ks], vb, oacc[nd], 0, 0, 0);
        }
    }
#pragma unroll
    for (int nd = 0; nd < 4; ++nd)
#pragma unroll
        for (int r = 0; r < 4; ++r) {
            const int i = i0 + il0 + r;
            const int col = (h << 6) + nd * 16 + l16;
            ATT[(size_t)(i * 8 + b) * 1024 + col] = (f16)(oacc[nd][r] * inv[r]);
        }
}

// ---------------------------------------------------------------------------
extern "C" void kernel_launch(void* const* d_in, const int* in_sizes, int n_in,
                              void* d_out, int out_size, void* d_ws, size_t ws_size,
                              hipStream_t stream)
{
    (void)in_sizes; (void)n_in; (void)out_size; (void)ws_size;

    const float* query  = (const float*)d_in[0];
    // d_in[1] (key), d_in[2] (value) unused: reference derives k,v from query.
    const float* rel_pe = (const float*)d_in[3];
    // d_in[4] attn_mask: causal, reproduced analytically (j > i).
    const float* utt    = (const float*)d_in[5];
    const int*   spk    = (const int*)d_in[6];
    const float* qw     = (const float*)d_in[7];
    const float* kw     = (const float*)d_in[8];
    const float* vw     = (const float*)d_in[9];
    const float* rw     = (const float*)d_in[10];
    const float* spke   = (const float*)d_in[11];
    const float* ow     = (const float*)d_in[12];

    char* ws = (char*)d_ws;
    f16* Qh   = (f16*)(ws);                  // 2 MB, head-major [n][t][d]
    f16* Kh   = (f16*)(ws + (2u  << 20));    // 2 MB, head-major [n][t][d]
    f16* VhT  = (f16*)(ws + (4u  << 20));    // 2 MB, transposed [n][d][t]
    f16* ATT  = (f16*)(ws + (6u  << 20));    // 2 MB, [t*8+b][e]
    float* CB = (float*)(ws + (8u  << 20));  // 64 KB  c[n][j]
    float* DD = (float*)(ws + (8u << 20) + (256u << 10)); // 128 KB dot[s][n][i]
    f16* ob   = (f16*)(ws + (10u << 20));    // 2 MB ow f16

    tof16ow_kernel<<<dim3(512), 256, 0, stream>>>(ow, ob);
    proj4rs_kernel<<<dim3(512), 256, 0, stream>>>(query, rel_pe, qw, kw, vw, rw,
                                                  spke, Qh, Kh, VhT, CB, DD);
    attn_mfma_kernel<<<dim3(256), 256, 0, stream>>>(Qh, Kh, VhT, CB, DD, spk, utt, ATT);
    out_kernel<<<dim3(256), 256, 0, stream>>>(ATT, ob, (float*)d_out);
}

// Round 17
// 48.859 us; speedup vs baseline: 1.1598x; 1.1598x over previous
//
#include <hip/hip_runtime.h>
#include <hip/hip_bf16.h>
#include <cstddef>
#include <cstdint>

// T=128, B=8, E=1024, H=16, D=64. GEMMs 1024^3.
// FINAL (r12-best revert, measured 48.87us): 4 dispatches:
//   tof16 -> proj4 (MFMA 64x128, 3-deep counted-vmcnt, setprio; epilogue
//   emits Qh/Kh head-major, VhT transposed, CB/DD side-products)
//   -> attn (single-barrier MFMA flash block) -> out (MFMA 64x64 -> d_out).
// r13-r16 probes (BK=128 long phases, 3 blk/CU, split-K2, reg-staged f32)
// all regressed or nulled; proj4's ~6000cyc/phase is environment-bound
// (workspace poison fills evict L2/L3 between replays -> per-phase memory
// tail latency), not structure-bound. This is the empirical optimum.

typedef _Float16 f16;
typedef __attribute__((ext_vector_type(8))) _Float16 f16x8;
typedef __attribute__((ext_vector_type(4))) float f32x4;

#define GLOBAL_TO_LDS(g, l) __builtin_amdgcn_global_load_lds( \
    (const __attribute__((address_space(1))) void*)(g),       \
    (__attribute__((address_space(3))) void*)(l), 16, 0, 0)

#define PIPE_SYNC(N) do {                                      \
    asm volatile("s_waitcnt vmcnt(" #N ")" ::: "memory");      \
    __builtin_amdgcn_s_barrier();                              \
    __builtin_amdgcn_sched_barrier(0);                         \
} while (0)

// ---------------------------------------------------------------------------
// fp32 -> fp16: 7 segments of 1M elems (query, rel_pe, qw, kw, vw, rw, ow).
// ---------------------------------------------------------------------------
struct Ptr7 { const float* s[7]; };

__global__ __launch_bounds__(256) void tof16_kernel(Ptr7 p, f16* dbase)
{
    const float* s = p.s[blockIdx.y];
    f16* d = dbase + (size_t)blockIdx.y * (1u << 20);
    const int i = (blockIdx.x * 256 + threadIdx.x) * 8;
    const float4 a = *(const float4*)(s + i);
    const float4 b = *(const float4*)(s + i + 4);
    f16x8 o;
    o[0] = (f16)a.x; o[1] = (f16)a.y; o[2] = (f16)a.z; o[3] = (f16)a.w;
    o[4] = (f16)b.x; o[5] = (f16)b.y; o[6] = (f16)b.z; o[7] = (f16)b.w;
    *(f16x8*)(d + i) = o;
}

// ---------------------------------------------------------------------------
// 3-deep counted-vmcnt MFMA GEMM core (K=1024, NT=16 steps of 64); fills acc.
// C[m][n] = sum_k A[m][k]*B[n][k], row stride 1024. 4 waves (2x2).
// T5: setprio(1) around the MFMA cluster. Swizzle: 16B slot ^= row&7 on the
// pre-swizzled GLOBAL source, LDS linear, mirrored on ds_read.
// ---------------------------------------------------------------------------
template <int TM, int TN>
__device__ __forceinline__ void gemm3ph_acc(const f16* __restrict__ A,
                                            const f16* __restrict__ B,
                                            int m0, int n0,
                                            f32x4 (&acc)[TM / 32][TN / 32])
{
    constexpr int AITS = TM / 32, BITS = TN / 32;
    constexpr int LD = AITS + BITS;                 // 6 / 5 / 4
    constexpr int FM = TM / 32, FN = TN / 32;
    __shared__ __attribute__((aligned(16))) f16 As0[TM * 64];
    __shared__ __attribute__((aligned(16))) f16 As1[TM * 64];
    __shared__ __attribute__((aligned(16))) f16 As2[TM * 64];
    __shared__ __attribute__((aligned(16))) f16 Bs0[TN * 64];
    __shared__ __attribute__((aligned(16))) f16 Bs1[TN * 64];
    __shared__ __attribute__((aligned(16))) f16 Bs2[TN * 64];
    const int tid = threadIdx.x;
    const int wave = tid >> 6, lane = tid & 63;
    const int wr = wave >> 1, wc = wave & 1;
    const int l16 = lane & 15, lk = lane >> 4;

    auto stage = [&](f16* as_, f16* bs_, int k0) {
#pragma unroll
        for (int it = 0; it < AITS; ++it) {
            const int ebase = it * 2048 + wave * 512;
            const int e = ebase + lane * 8;
            const int row = e >> 6, slot = (e >> 3) & 7;
            const int scol = (slot ^ (row & 7)) << 3;
            GLOBAL_TO_LDS(A + (size_t)(m0 + row) * 1024 + k0 + scol, as_ + ebase);
        }
#pragma unroll
        for (int it = 0; it < BITS; ++it) {
            const int ebase = it * 2048 + wave * 512;
            const int e = ebase + lane * 8;
            const int row = e >> 6, slot = (e >> 3) & 7;
            const int scol = (slot ^ (row & 7)) << 3;
            GLOBAL_TO_LDS(B + (size_t)(n0 + row) * 1024 + k0 + scol, bs_ + ebase);
        }
    };
    auto compute = [&](const f16* as_, const f16* bs_) {
#pragma unroll
        for (int ksl = 0; ksl < 2; ++ksl) {
            const int s = ksl * 4 + lk;
            f16x8 af[FM], bg[FN];
#pragma unroll
            for (int mi = 0; mi < FM; ++mi) {
                const int r = wr * (TM / 2) + mi * 16 + l16;
                af[mi] = *(const f16x8*)(as_ + r * 64 + ((s ^ (r & 7)) << 3));
            }
#pragma unroll
            for (int ni = 0; ni < FN; ++ni) {
                const int r = wc * (TN / 2) + ni * 16 + l16;
                bg[ni] = *(const f16x8*)(bs_ + r * 64 + ((s ^ (r & 7)) << 3));
            }
            __builtin_amdgcn_s_setprio(1);
#pragma unroll
            for (int mi = 0; mi < FM; ++mi)
#pragma unroll
                for (int ni = 0; ni < FN; ++ni)
                    acc[mi][ni] = __builtin_amdgcn_mfma_f32_16x16x32_f16(
                        af[mi], bg[ni], acc[mi][ni], 0, 0, 0);
            __builtin_amdgcn_s_setprio(0);
        }
    };
    auto sync_steady = [&]() {
        if constexpr (LD == 6) PIPE_SYNC(6);
        else if constexpr (LD == 5) PIPE_SYNC(5);
        else PIPE_SYNC(4);
    };

    stage(As0, Bs0, 0);
    stage(As1, Bs1, 64);
    int k = 0;
#pragma unroll 1
    for (int t = 0; t < 15; t += 3) {
        sync_steady();                               // drain tile t
        if (t + 2 < 16) stage(As2, Bs2, k + 128);
        compute(As0, Bs0);
        sync_steady();                               // drain tile t+1
        if (t + 3 < 16) stage(As0, Bs0, k + 192);
        compute(As1, Bs1);
        sync_steady();                               // drain tile t+2
        if (t + 4 < 16) stage(As1, Bs1, k + 256);
        compute(As2, Bs2);
        k += 192;
    }
    PIPE_SYNC(0);                                    // tail: tile 15
    compute(As0, Bs0);
}

// ---------------------------------------------------------------------------
// 4 projections, 64x128 tiles, grid 512. z = (bid&7)>>1 pins each GEMM to an
// XCD pair. Epilogues:
//   z=0: Qh head-major (newq = acc+sq0) + DD[s][n][i] row-dots vs spk_emb
//   z=1: Kh head-major;  z=2: VhT transposed [n][d][t]
//   z=3: CB[n][j] = sum_d sq0 . R  (R never materialized)
// ---------------------------------------------------------------------------
__global__ __launch_bounds__(256) void proj4_kernel(
    const f16* __restrict__ qf, const f16* __restrict__ rf,
    const f16* __restrict__ wbase, const float* __restrict__ spk_emb,
    f16* __restrict__ Qh, f16* __restrict__ Kh, f16* __restrict__ VhT,
    float* __restrict__ CB, float* __restrict__ DD)
{
    const int bid = blockIdx.x;
    const int z = (bid & 7) >> 1;
    const int w = ((bid >> 3) << 1) | (bid & 1);   // 0..127
    const int m0 = (w >> 3) << 6;                  // 16 M-tiles of 64
    const int n0 = (w & 7) << 7;                   // 8 N-tiles of 128
    const f16* A = (z == 3) ? rf : qf;
    const f16* W = wbase + ((size_t)z << 20);

    f32x4 acc[2][4] = {};
    gemm3ph_acc<64, 128>(A, W, m0, n0, acc);

    const int tid = threadIdx.x;
    const int wave = tid >> 6, lane = tid & 63;
    const int wr = wave >> 1, wc = wave & 1;
    const int l16 = lane & 15, lk = lane >> 4;
    const int h = (n0 >> 6) + wc;                  // head of this wave's cols

    if (z == 0) {
        float s0v[4], s1v[4];
#pragma unroll
        for (int ni = 0; ni < 4; ++ni) {
            const int c = (h << 6) + ni * 16 + l16;
            s0v[ni] = spk_emb[c];
            s1v[ni] = spk_emb[1024 + c];
        }
#pragma unroll
        for (int mi = 0; mi < 2; ++mi)
#pragma unroll
            for (int r = 0; r < 4; ++r) {
                const int row = m0 + wr * 32 + mi * 16 + lk * 4 + r;
                const int b = row & 7, t = row >> 3;
                float p0 = 0.f, p1 = 0.f;
#pragma unroll
                for (int ni = 0; ni < 4; ++ni) {
                    const float x = acc[mi][ni][r] + s0v[ni];
                    const int d = ni * 16 + l16;
                    Qh[(size_t)(((b << 4) + h) * 128 + t) * 64 + d] = (f16)x;
                    p0 = fmaf(x, s0v[ni], p0);
                    p1 = fmaf(x, s1v[ni], p1);
                }
#pragma unroll
                for (int off = 1; off < 16; off <<= 1) {
                    p0 += __shfl_xor(p0, off, 64);
                    p1 += __shfl_xor(p1, off, 64);
                }
                if (l16 == 0) {
                    const int n = (b << 4) + h;
                    DD[n * 128 + t] = p0;
                    DD[16384 + n * 128 + t] = p1;
                }
            }
    } else if (z == 3) {
        float s0v[4];
#pragma unroll
        for (int ni = 0; ni < 4; ++ni)
            s0v[ni] = spk_emb[(h << 6) + ni * 16 + l16];
#pragma unroll
        for (int mi = 0; mi < 2; ++mi)
#pragma unroll
            for (int r = 0; r < 4; ++r) {
                const int row = m0 + wr * 32 + mi * 16 + lk * 4 + r;
                const int b = row & 7, j = row >> 3;
                float p = 0.f;
#pragma unroll
                for (int ni = 0; ni < 4; ++ni)
                    p = fmaf(acc[mi][ni][r], s0v[ni], p);
#pragma unroll
                for (int off = 1; off < 16; off <<= 1)
                    p += __shfl_xor(p, off, 64);
                if (l16 == 0)
                    CB[((b << 4) + h) * 128 + j] = p;
            }
    } else {
        f16* dst = (z == 1) ? Kh : VhT;
#pragma unroll
        for (int mi = 0; mi < 2; ++mi)
#pragma unroll
            for (int r = 0; r < 4; ++r) {
                const int row = m0 + wr * 32 + mi * 16 + lk * 4 + r;
                const int b = row & 7, t = row >> 3;
#pragma unroll
                for (int ni = 0; ni < 4; ++ni) {
                    const int d = ni * 16 + l16;
                    const f16 x = (f16)acc[mi][ni][r];
                    if (z == 1)
                        dst[(size_t)(((b << 4) + h) * 128 + t) * 64 + d] = x;
                    else
                        dst[(size_t)(((b << 4) + h) * 64 + d) * 128 + t] = x;
                }
            }
    }
}

// Out projection: 64x64 tiles, full K, grid 256, writes f32 d_out directly.
__global__ __launch_bounds__(256) void out_kernel(
    const f16* __restrict__ ATT, const f16* __restrict__ owf,
    float* __restrict__ out)
{
    const int bid = blockIdx.x;
    const int m0 = (bid >> 4) << 6;                // 16 M-tiles of 64
    const int n0 = (bid & 15) << 6;                // 16 N-tiles of 64
    f32x4 acc[2][2] = {};
    gemm3ph_acc<64, 64>(ATT, owf, m0, n0, acc);
    const int tid = threadIdx.x;
    const int wave = tid >> 6, lane = tid & 63;
    const int wr = wave >> 1, wc = wave & 1;
    const int l16 = lane & 15, lk = lane >> 4;
#pragma unroll
    for (int mi = 0; mi < 2; ++mi)
#pragma unroll
        for (int ni = 0; ni < 2; ++ni)
#pragma unroll
            for (int r = 0; r < 4; ++r) {
                const int row = m0 + wr * 32 + mi * 16 + lk * 4 + r;
                const int col = n0 + wc * 32 + ni * 16 + l16;
                out[(size_t)row * 1024 + col] = acc[mi][ni][r];
            }
}

// ---------------------------------------------------------------------------
// MFMA attention, single-barrier body (verified r11/r12). Block = (n, half).
// a2 = utt * (spk ? dot1 : dot0); a3 = CB[127-i+j] (j<=i); masked score=1e-30.
// ---------------------------------------------------------------------------
__global__ __launch_bounds__(256) void attn_mfma_kernel(
    const f16* __restrict__ Qh, const f16* __restrict__ Kh,
    const f16* __restrict__ VhT,
    const float* __restrict__ CB, const float* __restrict__ DD,
    const int* __restrict__ spk_mask, const float* __restrict__ utt_mask,
    f16* __restrict__ ATT)
{
    __shared__ __attribute__((aligned(16))) char smem[58368];
    f16* nq = (f16*)smem;                  // [64][64]  swz   8192B
    f16* kt = (f16*)(smem + 8192);         // [128][64] swz  16384B
    f16* vt = (f16*)(smem + 24576);        // [64][128] swz  16384B
    f16* psb = (f16*)(smem + 40960);       // P tiles, 4KB/wave 16384B
    float* cbuf = (float*)(smem + 57344);  // 128 f32
    float* ddl  = (float*)(smem + 57856);  // dot0[64], dot1[64]

    const int bx = blockIdx.x, n = bx >> 1, half = bx & 1;
    const int b = n >> 4, h = n & 15, i0 = half << 6;
    const int tid = threadIdx.x, wave = tid >> 6, lane = tid & 63;
    const int l16 = lane & 15, lk = lane >> 4;
    const int il0 = wave * 16 + lk * 4;
    const size_t hb = (size_t)n * (128 * 64);

    // stage newQ [64][64], K [128][64], V^T [64][128]
#pragma unroll
    for (int it = 0; it < 2; ++it) {
        const int ebase = it * 2048 + wave * 512;
        const int e = ebase + lane * 8;
        const int row = e >> 6, slot = (e >> 3) & 7;
        const int scol = (slot ^ (row & 7)) << 3;
        GLOBAL_TO_LDS(Qh + hb + (size_t)(i0 + row) * 64 + scol, nq + ebase);
    }
#pragma unroll
    for (int it = 0; it < 4; ++it) {
        const int ebase = it * 2048 + wave * 512;
        const int e = ebase + lane * 8;
        const int row = e >> 6, slot = (e >> 3) & 7;
        const int scol = (slot ^ (row & 7)) << 3;
        GLOBAL_TO_LDS(Kh + hb + (size_t)row * 64 + scol, kt + ebase);
    }
#pragma unroll
    for (int it = 0; it < 4; ++it) {
        const int ebase = it * 2048 + wave * 512;
        const int e = ebase + lane * 8;
        const int row = e >> 7, slot = (e >> 3) & 15;
        const int scol = (slot ^ (row & 7)) << 3;
        GLOBAL_TO_LDS(VhT + hb + (size_t)row * 128 + scol, vt + ebase);
    }

    // CB/DD -> LDS (tiny; complete by the barrier)
    if (tid < 128) {
        cbuf[tid] = CB[n * 128 + tid];
    } else {
        const int t2 = tid - 128;
        ddl[t2] = DD[(t2 >> 6) * 16384 + n * 128 + i0 + (t2 & 63)];
    }

    // mask hoist into registers
    float du[8][4];
    int   sm[8][4];
#pragma unroll
    for (int ni = 0; ni < 8; ++ni) {
        const int j = ni * 16 + l16;
#pragma unroll
        for (int r = 0; r < 4; ++r) {
            const int i = i0 + il0 + r;
            du[ni][r] = utt_mask[((size_t)n * 128 + i) * 128 + j];
            sm[ni][r] = spk_mask[((size_t)b * 128 + i) * 128 + j];
        }
    }
    __syncthreads();

    // QK^T: per-wave M=16 rows, N=128, K=64
    const int iw = wave * 16 + l16;
    f16x8 af[2];
#pragma unroll
    for (int ksl = 0; ksl < 2; ++ksl) {
        const int s = ksl * 4 + lk;
        af[ksl] = *(const f16x8*)(nq + iw * 64 + ((s ^ (iw & 7)) << 3));
    }
    f32x4 sacc[8] = {};
#pragma unroll
    for (int ksl = 0; ksl < 2; ++ksl) {
        const int s = ksl * 4 + lk;
#pragma unroll
        for (int ni = 0; ni < 8; ++ni) {
            const int j = ni * 16 + l16;
            const f16x8 bg = *(const f16x8*)(kt + j * 64 + ((s ^ (j & 7)) << 3));
            sacc[ni] = __builtin_amdgcn_mfma_f32_16x16x32_f16(af[ksl], bg, sacc[ni], 0, 0, 0);
        }
    }

    float sc[8][4];
#pragma unroll
    for (int ni = 0; ni < 8; ++ni) {
        const int j = ni * 16 + l16;
#pragma unroll
        for (int r = 0; r < 4; ++r) {
            const int il = il0 + r, i = i0 + il;
            const float a2 = du[ni][r] * (sm[ni][r] ? ddl[64 + il] : ddl[il]);
            const float a3 = (j <= i) ? cbuf[127 - i + j] : 0.f;
            const float v = (sacc[ni][r] + a2 + a3) * 0.125f;
            sc[ni][r] = (j > i) ? 1e-30f : v;
        }
    }
    float inv[4];
    f16* ps = psb + wave * 2048;
#pragma unroll
    for (int r = 0; r < 4; ++r) {
        float m = sc[0][r];
#pragma unroll
        for (int ni = 1; ni < 8; ++ni) m = fmaxf(m, sc[ni][r]);
#pragma unroll
        for (int off = 8; off > 0; off >>= 1) m = fmaxf(m, __shfl_xor(m, off, 64));
        float ssum = 0.f;
#pragma unroll
        for (int ni = 0; ni < 8; ++ni) {
            const float e = __expf(sc[ni][r] - m);
            sc[ni][r] = e;
            ssum += e;
        }
#pragma unroll
        for (int off = 8; off > 0; off >>= 1) ssum += __shfl_xor(ssum, off, 64);
        inv[r] = 1.f / ssum;
    }
#pragma unroll
    for (int ni = 0; ni < 8; ++ni) {
        const int j = ni * 16 + l16;
#pragma unroll
        for (int r = 0; r < 4; ++r) {
            const int il = lk * 4 + r;
            ps[il * 128 + ((((j >> 3) ^ (il & 7)) << 3) | (j & 7))] = (f16)sc[ni][r];
        }
    }

    // PV: M=16, N=64, K=128 (wave-local P; no barrier needed)
    f16x8 pa[4];
#pragma unroll
    for (int ks = 0; ks < 4; ++ks) {
        const int slot = ks * 4 + lk;
        pa[ks] = *(const f16x8*)(ps + l16 * 128 + ((slot ^ (l16 & 7)) << 3));
    }
    f32x4 oacc[4] = {};
#pragma unroll
    for (int ks = 0; ks < 4; ++ks) {
        const int slot = ks * 4 + lk;
#pragma unroll
        for (int nd = 0; nd < 4; ++nd) {
            const int d = nd * 16 + l16;
            const f16x8 vb = *(const f16x8*)(vt + d * 128 + ((slot ^ (d & 7)) << 3));
            oacc[nd] = __builtin_amdgcn_mfma_f32_16x16x32_f16(pa[ks], vb, oacc[nd], 0, 0, 0);
        }
    }
#pragma unroll
    for (int nd = 0; nd < 4; ++nd)
#pragma unroll
        for (int r = 0; r < 4; ++r) {
            const int i = i0 + il0 + r;
            const int col = (h << 6) + nd * 16 + l16;
            ATT[(size_t)(i * 8 + b) * 1024 + col] = (f16)(oacc[nd][r] * inv[r]);
        }
}

// ---------------------------------------------------------------------------
extern "C" void kernel_launch(void* const* d_in, const int* in_sizes, int n_in,
                              void* d_out, int out_size, void* d_ws, size_t ws_size,
                              hipStream_t stream)
{
    (void)in_sizes; (void)n_in; (void)out_size; (void)ws_size;

    const float* query  = (const float*)d_in[0];
    // d_in[1] (key), d_in[2] (value) unused: reference derives k,v from query.
    const float* rel_pe = (const float*)d_in[3];
    // d_in[4] attn_mask: causal, reproduced analytically (j > i).
    const float* utt    = (const float*)d_in[5];
    const int*   spk    = (const int*)d_in[6];
    const float* qw     = (const float*)d_in[7];
    const float* kw     = (const float*)d_in[8];
    const float* vw     = (const float*)d_in[9];
    const float* rw     = (const float*)d_in[10];
    const float* spke   = (const float*)d_in[11];
    const float* ow     = (const float*)d_in[12];

    char* ws = (char*)d_ws;
    f16* Qh   = (f16*)(ws);                  // 2 MB, head-major [n][t][d]
    f16* Kh   = (f16*)(ws + (2u  << 20));    // 2 MB, head-major [n][t][d]
    f16* VhT  = (f16*)(ws + (4u  << 20));    // 2 MB, transposed [n][d][t]
    f16* ATT  = (f16*)(ws + (6u  << 20));    // 2 MB, [t*8+b][e]
    float* CB = (float*)(ws + (8u  << 20));  // 64 KB  c[n][j]
    float* DD = (float*)(ws + (8u << 20) + (256u << 10)); // 128 KB dot[s][n][i]
    f16* fb   = (f16*)(ws + (10u << 20));    // 7 x 2 MB f16 conversions

    f16* qf = fb;                  // query
    f16* rf = fb + (1u << 20);     // rel_pe
    f16* wb = fb + (2u << 20);     // qw,kw,vw,rw
    f16* ob = fb + (6u << 20);     // ow

    Ptr7 p7;
    p7.s[0] = query; p7.s[1] = rel_pe; p7.s[2] = qw; p7.s[3] = kw;
    p7.s[4] = vw; p7.s[5] = rw; p7.s[6] = ow;

    tof16_kernel<<<dim3(512, 7), 256, 0, stream>>>(p7, fb);
    proj4_kernel<<<dim3(512), 256, 0, stream>>>(qf, rf, wb, spke, Qh, Kh, VhT, CB, DD);
    attn_mfma_kernel<<<dim3(256), 256, 0, stream>>>(Qh, Kh, VhT, CB, DD, spk, utt, ATT);
    out_kernel<<<dim3(256), 256, 0, stream>>>(ATT, ob, (float*)d_out);
}